// Round 9
// baseline (354.809 us; speedup 1.0000x reference)
//
#include <hip/hip_runtime.h>

#define NN 100000
#define EE 1600000
#define GG 1000
#define BN_EPS 1e-5f
#define NB1 391        // ceil(NN/256)

// ---------- segment-max via monotonic uint encoding ----------
__device__ __forceinline__ unsigned encf(float f){
  unsigned u = __float_as_uint(f);
  return (u & 0x80000000u) ? ~u : (u | 0x80000000u);
}
__device__ __forceinline__ float dec0(unsigned e){
  unsigned u = (e & 0x80000000u) ? (e & 0x7fffffffu) : ~e;
  float f = __uint_as_float(u);
  return isfinite(f) ? f : 0.0f;   // init-0 sentinel decodes to NaN -> 0 (empty segment)
}
// ---------- bf16 helpers (RNE) ----------
__device__ __forceinline__ unsigned short f2bf(float f){
  unsigned u = __float_as_uint(f);
  u += 0x7FFFu + ((u >> 16) & 1u);
  return (unsigned short)(u >> 16);
}
__device__ __forceinline__ float bf2f(unsigned short s){
  return __uint_as_float(((unsigned)s) << 16);
}

// ---------- CSR build: count -> alloc(scan-free) -> scatter ----------
__global__ void k_count(const int* __restrict__ ei, const int* __restrict__ ew,
                        int* __restrict__ cnt){
  int e = blockIdx.x*256 + threadIdx.x;
  if (e < EE && ew[e] == 1) atomicAdd(&cnt[ei[EE + e]], 1);
}

// Per-block LDS scan + one global atomicAdd per block: assigns each node a
// disjoint CSR range (arbitrary inter-block order — gather only sums).
__global__ __launch_bounds__(256) void k_alloc(const int* __restrict__ cnt,
    int* __restrict__ ctr, float* __restrict__ dinv,
    int* __restrict__ rowstart, int* __restrict__ fill){
  __shared__ int sm[256];
  __shared__ int base;
  const int i = blockIdx.x*256 + threadIdx.x;
  const int v = (i < NN) ? cnt[i] : 0;
  sm[threadIdx.x] = v;
  __syncthreads();
  for (int off = 1; off < 256; off <<= 1){
    int t = (threadIdx.x >= off) ? sm[threadIdx.x - off] : 0;
    __syncthreads();
    sm[threadIdx.x] += t;
    __syncthreads();
  }
  if (threadIdx.x == 255) base = atomicAdd(ctr, sm[255]);
  __syncthreads();
  if (i < NN){
    int rs = base + sm[threadIdx.x] - v;
    rowstart[i] = rs; fill[i] = rs;
    dinv[i] = rsqrtf((float)v + 1.0f);   // +1 self loop
  }
}

__global__ void k_scatter(const int* __restrict__ ei, const int* __restrict__ ew,
                          int* __restrict__ fill, int* __restrict__ csr){
  int e = blockIdx.x*256 + threadIdx.x;
  if (e < EE && ew[e] == 1){
    int c = ei[EE + e];
    int pos = atomicAdd(&fill[c], 1);
    csr[pos] = ei[e];
  }
}

// ---------- GEMM1: Y1 = bf16(x@W1 + b1), accumulate column sum/sumsq (f32) ----------
__global__ __launch_bounds__(256) void k_gemm1(const float* __restrict__ x,
    const float* __restrict__ W1, const float* __restrict__ b1,
    unsigned short* __restrict__ Y1b, float* __restrict__ stats){
  __shared__ float xs[32*132];     // 32 rows x 128, padded
  __shared__ float Ws[128*32];
  __shared__ float red[64];
  const int tid = threadIdx.x;
  for (int j = tid; j < 1024; j += 256) ((float4*)Ws)[j] = ((const float4*)W1)[j];
  const int r = tid >> 3, cg = tid & 7;
  const float4 bv = ((const float4*)b1)[cg];
  float s0=0,s1=0,s2=0,s3=0,q0=0,q1=0,q2=0,q3=0;
  for (int tile = blockIdx.x; tile < 3125; tile += gridDim.x){
    __syncthreads();
    for (int j = tid; j < 1024; j += 256){
      int rr = j >> 5, kk = j & 31;
      *(float4*)&xs[rr*132 + kk*4] = ((const float4*)x)[(size_t)tile*1024 + j];
    }
    __syncthreads();
    float a0=bv.x, a1=bv.y, a2=bv.z, a3=bv.w;
    const float* xr = &xs[r*132];
    const float* wc = &Ws[cg*4];
    #pragma unroll 8
    for (int k = 0; k < 128; k++){
      float xv = xr[k];
      float4 w = *(const float4*)&wc[k*32];
      a0 += xv*w.x; a1 += xv*w.y; a2 += xv*w.z; a3 += xv*w.w;
    }
    ushort4 o; o.x=f2bf(a0); o.y=f2bf(a1); o.z=f2bf(a2); o.w=f2bf(a3);
    ((ushort4*)Y1b)[(size_t)(tile*32 + r)*8 + cg] = o;
    s0+=a0; s1+=a1; s2+=a2; s3+=a3;
    q0+=a0*a0; q1+=a1*a1; q2+=a2*a2; q3+=a3*a3;
  }
  __syncthreads();
  if (tid < 64) red[tid] = 0.f;
  __syncthreads();
  atomicAdd(&red[cg*4+0], s0); atomicAdd(&red[cg*4+1], s1);
  atomicAdd(&red[cg*4+2], s2); atomicAdd(&red[cg*4+3], s3);
  atomicAdd(&red[32+cg*4+0], q0); atomicAdd(&red[32+cg*4+1], q1);
  atomicAdd(&red[32+cg*4+2], q2); atomicAdd(&red[32+cg*4+3], q3);
  __syncthreads();
  if (tid < 64) atomicAdd(&stats[tid], red[tid]);
}

// ---------- MLP2: Y2 = bf16(relu(bn1(Y1))@W2 + b2) (BN inlined), accumulate stats2 ----------
__global__ __launch_bounds__(256) void k_mlp2(const unsigned short* __restrict__ Y1b,
    const float* __restrict__ W2, const float* __restrict__ b2,
    const float* __restrict__ g1, const float* __restrict__ bt1,
    float* __restrict__ stats, unsigned short* __restrict__ Y2b){
  __shared__ float hs[32*36];
  __shared__ float Ws[32*32];
  __shared__ float red[64];
  __shared__ float scs[32], shs[32];
  const int tid = threadIdx.x;
  ((float4*)Ws)[tid] = ((const float4*)W2)[tid];
  if (tid < 32){
    float mean = stats[tid] * (1.0f/NN);
    float var  = stats[32 + tid] * (1.0f/NN) - mean*mean;
    float s = g1[tid] * rsqrtf(fmaxf(var, 0.0f) + BN_EPS);
    scs[tid] = s; shs[tid] = bt1[tid] - mean*s;
  }
  __syncthreads();
  const int r = tid >> 3, cg = tid & 7;
  const float4 bv = ((const float4*)b2)[cg];
  const float4 sc = *(const float4*)&scs[cg*4];
  const float4 sh = *(const float4*)&shs[cg*4];
  float s0=0,s1=0,s2=0,s3=0,q0=0,q1=0,q2=0,q3=0;
  for (int tile = blockIdx.x; tile < 3125; tile += gridDim.x){
    __syncthreads();
    {
      ushort4 u = ((const ushort4*)Y1b)[(size_t)tile*256 + tid];
      float4 v;
      v.x = fmaxf(fmaf(bf2f(u.x), sc.x, sh.x), 0.f);
      v.y = fmaxf(fmaf(bf2f(u.y), sc.y, sh.y), 0.f);
      v.z = fmaxf(fmaf(bf2f(u.z), sc.z, sh.z), 0.f);
      v.w = fmaxf(fmaf(bf2f(u.w), sc.w, sh.w), 0.f);
      *(float4*)&hs[r*36 + cg*4] = v;
    }
    __syncthreads();
    float a0=bv.x, a1=bv.y, a2=bv.z, a3=bv.w;
    const float* hr = &hs[r*36];
    const float* wc = &Ws[cg*4];
    #pragma unroll
    for (int k = 0; k < 32; k++){
      float h = hr[k];
      float4 w = *(const float4*)&wc[k*32];
      a0 += h*w.x; a1 += h*w.y; a2 += h*w.z; a3 += h*w.w;
    }
    ushort4 o; o.x=f2bf(a0); o.y=f2bf(a1); o.z=f2bf(a2); o.w=f2bf(a3);
    ((ushort4*)Y2b)[(size_t)(tile*32 + r)*8 + cg] = o;
    s0+=a0; s1+=a1; s2+=a2; s3+=a3;
    q0+=a0*a0; q1+=a1*a1; q2+=a2*a2; q3+=a3*a3;
  }
  __syncthreads();
  if (tid < 64) red[tid] = 0.f;
  __syncthreads();
  atomicAdd(&red[cg*4+0], s0); atomicAdd(&red[cg*4+1], s1);
  atomicAdd(&red[cg*4+2], s2); atomicAdd(&red[cg*4+3], s3);
  atomicAdd(&red[32+cg*4+0], q0); atomicAdd(&red[32+cg*4+1], q1);
  atomicAdd(&red[32+cg*4+2], q2); atomicAdd(&red[32+cg*4+3], q3);
  __syncthreads();
  if (tid < 64) atomicAdd(&stats[128 + tid], red[tid]);
}

// ---------- layer0: h1 = relu(bn2(Y2)) (BN inlined); Pool0 <- max(h1@Wl0+bl0);
//            Hs1 = bf16((h1@Wg1)*dinv) ----------
__global__ __launch_bounds__(256) void k_layer0(const unsigned short* __restrict__ Y2b,
    const float* __restrict__ stats, const float* __restrict__ g2,
    const float* __restrict__ bt2, const float* __restrict__ Wg1,
    const float* __restrict__ Wl0, const float* __restrict__ bl0,
    const float* __restrict__ dinv, const int* __restrict__ batch,
    unsigned short* __restrict__ Hs1, unsigned* __restrict__ Pool0){
  __shared__ float hs[32*36];
  __shared__ float Wg[32*64];
  __shared__ float Wl[320];
  __shared__ float bl[10];
  __shared__ float scs[32], shs[32];
  const int tid = threadIdx.x;
  ((float4*)Wg)[tid]       = ((const float4*)Wg1)[tid];
  ((float4*)Wg)[tid + 256] = ((const float4*)Wg1)[tid + 256];
  for (int j = tid; j < 320; j += 256) Wl[j] = Wl0[j];
  if (tid < 10)  bl[tid] = bl0[tid];
  if (tid < 32){
    float mean = stats[128 + tid] * (1.0f/NN);
    float var  = stats[160 + tid] * (1.0f/NN) - mean*mean;
    float s = g2[tid] * rsqrtf(fmaxf(var, 0.0f) + BN_EPS);
    scs[tid] = s; shs[tid] = bt2[tid] - mean*s;
  }
  __syncthreads();
  {
    const int rr = tid >> 3, kk = tid & 7;
    const float4 sc = *(const float4*)&scs[kk*4];
    const float4 sh = *(const float4*)&shs[kk*4];
    ushort4 u = ((const ushort4*)Y2b)[(size_t)blockIdx.x*256 + tid];
    float4 v;
    v.x = fmaxf(fmaf(bf2f(u.x), sc.x, sh.x), 0.f);
    v.y = fmaxf(fmaf(bf2f(u.y), sc.y, sh.y), 0.f);
    v.z = fmaxf(fmaf(bf2f(u.z), sc.z, sh.z), 0.f);
    v.w = fmaxf(fmaf(bf2f(u.w), sc.w, sh.w), 0.f);
    *(float4*)&hs[rr*36 + kk*4] = v;
  }
  __syncthreads();
  const int w = tid >> 6, f = tid & 63;
  for (int i = 0; i < 8; i++){
    const int r = w*8 + i;
    const int row = blockIdx.x*32 + r;
    const float* hr = &hs[r*36];
    float acc = 0.f;
    #pragma unroll
    for (int k = 0; k < 32; k++) acc += hr[k]*Wg[k*64 + f];
    Hs1[(size_t)row*64 + f] = f2bf(acc * dinv[row]);
    if (f < 10){
      float p = bl[f];
      #pragma unroll
      for (int k = 0; k < 32; k++) p += hr[k]*Wl[k*10 + f];
      atomicMax(&Pool0[batch[row]*10 + f], encf(p));
    }
  }
}

// ---------- shared gather body: acc = sum of Hs rows (8-way unrolled) ----------
__device__ __forceinline__ float gather_sum(const unsigned short* __restrict__ Hs,
    const int* __restrict__ csr, int s, int e, int f){
  float acc = 0.f;
  int j = s;
  for (; j + 7 < e; j += 8){
    const int r0 = csr[j],   r1 = csr[j+1], r2 = csr[j+2], r3 = csr[j+3];
    const int r4 = csr[j+4], r5 = csr[j+5], r6 = csr[j+6], r7 = csr[j+7];
    float t0 = bf2f(Hs[(size_t)r0*64 + f]);
    float t1 = bf2f(Hs[(size_t)r1*64 + f]);
    float t2 = bf2f(Hs[(size_t)r2*64 + f]);
    float t3 = bf2f(Hs[(size_t)r3*64 + f]);
    float t4 = bf2f(Hs[(size_t)r4*64 + f]);
    float t5 = bf2f(Hs[(size_t)r5*64 + f]);
    float t6 = bf2f(Hs[(size_t)r6*64 + f]);
    float t7 = bf2f(Hs[(size_t)r7*64 + f]);
    acc += ((t0 + t1) + (t2 + t3)) + ((t4 + t5) + (t6 + t7));
  }
  for (; j + 3 < e; j += 4){
    const int r0 = csr[j], r1 = csr[j+1], r2 = csr[j+2], r3 = csr[j+3];
    float t0 = bf2f(Hs[(size_t)r0*64 + f]);
    float t1 = bf2f(Hs[(size_t)r1*64 + f]);
    float t2 = bf2f(Hs[(size_t)r2*64 + f]);
    float t3 = bf2f(Hs[(size_t)r3*64 + f]);
    acc += (t0 + t1) + (t2 + t3);
  }
  for (; j < e; j++) acc += bf2f(Hs[(size_t)csr[j]*64 + f]);
  return acc;
}

// ---------- pool epilogue: LDS-combine 4 nodes/block (batch sorted) ----------
__device__ __forceinline__ void pool_epilogue(float h, int w, int f, int c,
    const int* __restrict__ batch, unsigned* __restrict__ Pool,
    float (*sm)[64], int* sb){
  sm[w][f] = h;
  if (f == 0) sb[w] = batch[c];
  __syncthreads();
  if (w == 0){
    const int b0 = sb[0], b1 = sb[1], b2 = sb[2], b3 = sb[3];
    if (b0 == b3){
      float m = fmaxf(fmaxf(sm[0][f], sm[1][f]), fmaxf(sm[2][f], sm[3][f]));
      atomicMax(&Pool[b0*64 + f], encf(m));
    } else {
      atomicMax(&Pool[b0*64 + f], encf(sm[0][f]));
      atomicMax(&Pool[b1*64 + f], encf(sm[1][f]));
      atomicMax(&Pool[b2*64 + f], encf(sm[2][f]));
      atomicMax(&Pool[b3*64 + f], encf(sm[3][f]));
    }
  }
}

// ---------- agg1: h2 = dc*(sum Hs1[r] + Hs1[c]) + bg1; pool; store bf16 h2 ----------
__global__ __launch_bounds__(256) void k_agg1(const unsigned short* __restrict__ Hs,
    const float* __restrict__ dinv, const int* __restrict__ rowstart,
    const int* __restrict__ cnt, const int* __restrict__ csr,
    const float* __restrict__ bias, const int* __restrict__ batch,
    unsigned short* __restrict__ H2b, unsigned* __restrict__ Pool){
  __shared__ float sm[4][64];
  __shared__ int sb[4];
  const int w = threadIdx.x >> 6, f = threadIdx.x & 63;
  const int c = blockIdx.x*4 + w;
  const int s = rowstart[c], e = s + cnt[c];
  float acc = gather_sum(Hs, csr, s, e, f);
  const float dc = dinv[c];
  const float h = fmaf(acc + bf2f(Hs[(size_t)c*64 + f]), dc, bias[f]);
  H2b[(size_t)c*64 + f] = f2bf(h);
  pool_epilogue(h, w, f, c, batch, Pool, sm, sb);
}

// ---------- agg2: h3 = dc*(sum Hs2[r] + Hs2[c]) + bg2; pool only ----------
__global__ __launch_bounds__(256) void k_agg2(const unsigned short* __restrict__ Hs,
    const float* __restrict__ dinv, const int* __restrict__ rowstart,
    const int* __restrict__ cnt, const int* __restrict__ csr,
    const float* __restrict__ bias, const int* __restrict__ batch,
    unsigned* __restrict__ Pool){
  __shared__ float sm[4][64];
  __shared__ int sb[4];
  const int w = threadIdx.x >> 6, f = threadIdx.x & 63;
  const int c = blockIdx.x*4 + w;
  const int s = rowstart[c], e = s + cnt[c];
  float acc = gather_sum(Hs, csr, s, e, f);
  const float dc = dinv[c];
  const float h = fmaf(acc + bf2f(Hs[(size_t)c*64 + f]), dc, bias[f]);
  pool_epilogue(h, w, f, c, batch, Pool, sm, sb);
}

// ---------- layer1 GEMM: Hs2 = bf16((h2 @ Wg2) * dinv) ----------
__global__ __launch_bounds__(256) void k_layer1(const unsigned short* __restrict__ H2b,
    const float* __restrict__ Wg2, const float* __restrict__ dinv,
    unsigned short* __restrict__ Hs2){
  __shared__ float as[32*68];
  __shared__ float Wg[64*64];
  const int tid = threadIdx.x;
  #pragma unroll
  for (int j = 0; j < 4; j++) ((float4*)Wg)[tid + j*256] = ((const float4*)Wg2)[tid + j*256];
  {
    // 32 rows x 64 bf16 = 2048 ushorts; 8 per thread
    const int rr = tid >> 3, kk = tid & 7;
    ushort4 v0 = ((const ushort4*)H2b)[(size_t)blockIdx.x*512 + tid*2];
    ushort4 v1 = ((const ushort4*)H2b)[(size_t)blockIdx.x*512 + tid*2 + 1];
    float* dst = &as[rr*68 + kk*8];
    dst[0]=bf2f(v0.x); dst[1]=bf2f(v0.y); dst[2]=bf2f(v0.z); dst[3]=bf2f(v0.w);
    dst[4]=bf2f(v1.x); dst[5]=bf2f(v1.y); dst[6]=bf2f(v1.z); dst[7]=bf2f(v1.w);
  }
  __syncthreads();
  const int w = tid >> 6, f = tid & 63;
  for (int i = 0; i < 8; i++){
    const int r = w*8 + i;
    const int row = blockIdx.x*32 + r;
    const float* ar = &as[r*68];
    float acc = 0.f;
    #pragma unroll
    for (int k = 0; k < 64; k++) acc += ar[k]*Wg[k*64 + f];
    Hs2[(size_t)row*64 + f] = f2bf(acc * dinv[row]);
  }
}

// ---------- final: out = P0 + P1@Wl1+bl1 + P2@Wl2+bl2 ----------
__global__ __launch_bounds__(256) void k_final(const unsigned* __restrict__ P0,
    const unsigned* __restrict__ P1, const unsigned* __restrict__ P2,
    const float* __restrict__ Wl1, const float* __restrict__ bl1,
    const float* __restrict__ Wl2, const float* __restrict__ bl2,
    float* __restrict__ out){
  const int t = blockIdx.x*256 + threadIdx.x;
  const int g = t >> 4, c = t & 15;
  if (g >= GG || c >= 10) return;
  float acc = dec0(P0[g*10 + c]) + bl1[c] + bl2[c];
  for (int f = 0; f < 64; f++){
    acc += dec0(P1[g*64 + f]) * Wl1[f*10 + c];
    acc += dec0(P2[g*64 + f]) * Wl2[f*10 + c];
  }
  out[g*10 + c] = acc;
}

extern "C" void kernel_launch(void* const* d_in, const int* in_sizes, int n_in,
                              void* d_out, int out_size, void* d_ws, size_t ws_size,
                              hipStream_t stream){
  const float* x   = (const float*)d_in[0];
  const int*   ei  = (const int*)d_in[1];
  const int*   ew  = (const int*)d_in[2];
  const int*   bat = (const int*)d_in[3];
  const float* W1  = (const float*)d_in[5],  *b1  = (const float*)d_in[6];
  const float* g1  = (const float*)d_in[7],  *bt1 = (const float*)d_in[8];
  const float* W2  = (const float*)d_in[9],  *b2  = (const float*)d_in[10];
  const float* g2  = (const float*)d_in[11], *bt2 = (const float*)d_in[12];
  const float* Wl0 = (const float*)d_in[13], *bl0 = (const float*)d_in[14];
  const float* Wg1 = (const float*)d_in[15], *bg1 = (const float*)d_in[16];
  const float* Wl1 = (const float*)d_in[17], *bl1 = (const float*)d_in[18];
  const float* Wg2 = (const float*)d_in[19], *bg2 = (const float*)d_in[20];
  const float* Wl2 = (const float*)d_in[21], *bl2 = (const float*)d_in[22];

  float* ws = (float*)d_ws;
  // workspace layout (4B elems). Zeroed prefix: cnt | ctr | stats | P0 | P1 | P2
  const size_t oCnt   = 0;                         // NN ints
  const size_t oCtr   = NN;                        // 8 (cursor + pad)
  const size_t oStats = NN + 8;                    // 256
  const size_t oP0    = oStats + 256;              // G*10
  const size_t oP1    = oP0 + (size_t)GG*10;       // G*64
  const size_t oP2    = oP1 + (size_t)GG*64;       // G*64
  const size_t oZEnd  = oP2 + (size_t)GG*64;       // zero prefix end
  const size_t oDinv  = oZEnd;                     // NN
  const size_t oRS    = oDinv + NN;                // NN
  const size_t oFill  = oRS + NN;                  // NN
  const size_t oCsr   = oFill + NN;                // EE
  const size_t oR1    = oCsr + EE;                 // NN*16 (Y1b bf16: NN*32)
  const size_t oR2    = oR1 + (size_t)NN*16;       // NN*16 (Y2b bf16: NN*32)
  const size_t oR3    = oR2 + (size_t)NN*16;       // NN*32 (Hs1 bf16: NN*64; later Hs2)
  const size_t oR4    = oR3 + (size_t)NN*32;       // NN*32 (H2b bf16: NN*64)

  int*   cnt   = (int*)(ws + oCnt);
  int*   ctr   = (int*)(ws + oCtr);
  float* stats = ws + oStats;
  unsigned* P0 = (unsigned*)(ws + oP0);
  unsigned* P1 = (unsigned*)(ws + oP1);
  unsigned* P2 = (unsigned*)(ws + oP2);
  float* dinv  = ws + oDinv;
  int*   rs    = (int*)(ws + oRS);
  int*   fill  = (int*)(ws + oFill);
  int*   csr   = (int*)(ws + oCsr);
  unsigned short* Y1b = (unsigned short*)(ws + oR1);
  unsigned short* Y2b = (unsigned short*)(ws + oR2);
  unsigned short* Hs1 = (unsigned short*)(ws + oR3);
  unsigned short* Hs2 = (unsigned short*)(ws + oR3);   // reuse after Hs1 consumed
  unsigned short* H2b = (unsigned short*)(ws + oR4);

  (void)hipMemsetAsync(d_ws, 0, oZEnd*sizeof(float), stream);

  // CSR build (3 dispatches; arbitrary range packing — gather only sums)
  k_count  <<<EE/256, 256, 0, stream>>>(ei, ew, cnt);
  k_alloc  <<<NB1, 256, 0, stream>>>(cnt, ctr, dinv, rs, fill);
  k_scatter<<<EE/256, 256, 0, stream>>>(ei, ew, fill, csr);

  // MLP + heads
  k_gemm1<<<1536, 256, 0, stream>>>(x, W1, b1, Y1b, stats);
  k_mlp2 <<<1536, 256, 0, stream>>>(Y1b, W2, b2, g1, bt1, stats, Y2b);
  k_layer0<<<3125, 256, 0, stream>>>(Y2b, stats, g2, bt2, Wg1, Wl0, bl0, dinv, bat, Hs1, P0);
  k_agg1 <<<NN/4, 256, 0, stream>>>(Hs1, dinv, rs, cnt, csr, bg1, bat, H2b, P1);
  k_layer1<<<3125, 256, 0, stream>>>(H2b, Wg2, dinv, Hs2);
  k_agg2 <<<NN/4, 256, 0, stream>>>(Hs2, dinv, rs, cnt, csr, bg2, bat, P2);
  k_final<<<(GG*16 + 255)/256, 256, 0, stream>>>(P0, P1, P2, Wl1, bl1, Wl2, bl2, (float*)d_out);
}

// Round 10
// 340.347 us; speedup vs baseline: 1.0425x; 1.0425x over previous
//
#include <hip/hip_runtime.h>

#define NN 100000
#define EE 1600000
#define GG 1000
#define BN_EPS 1e-5f
#define NB1 391        // ceil(NN/256)
#define NTB 782        // ceil(NN/128) tiles for dense kernels

// ---------- segment-max via monotonic uint encoding ----------
__device__ __forceinline__ unsigned encf(float f){
  unsigned u = __float_as_uint(f);
  return (u & 0x80000000u) ? ~u : (u | 0x80000000u);
}
__device__ __forceinline__ float dec0(unsigned e){
  unsigned u = (e & 0x80000000u) ? (e & 0x7fffffffu) : ~e;
  float f = __uint_as_float(u);
  return isfinite(f) ? f : 0.0f;   // init-0 sentinel decodes to NaN -> 0 (empty segment)
}
// ---------- bf16 helpers (RNE) ----------
__device__ __forceinline__ unsigned short f2bf(float f){
  unsigned u = __float_as_uint(f);
  u += 0x7FFFu + ((u >> 16) & 1u);
  return (unsigned short)(u >> 16);
}
__device__ __forceinline__ float bf2f(unsigned short s){
  return __uint_as_float(((unsigned)s) << 16);
}

// ---------- CSR build: count -> alloc(scan-free) -> scatter ----------
__global__ void k_count(const int* __restrict__ ei, const int* __restrict__ ew,
                        int* __restrict__ cnt){
  int e = blockIdx.x*256 + threadIdx.x;
  if (e < EE && ew[e] == 1) atomicAdd(&cnt[ei[EE + e]], 1);
}

__global__ __launch_bounds__(256) void k_alloc(const int* __restrict__ cnt,
    int* __restrict__ ctr, float* __restrict__ dinv,
    int* __restrict__ rowstart, int* __restrict__ fill){
  __shared__ int sm[256];
  __shared__ int base;
  const int i = blockIdx.x*256 + threadIdx.x;
  const int v = (i < NN) ? cnt[i] : 0;
  sm[threadIdx.x] = v;
  __syncthreads();
  for (int off = 1; off < 256; off <<= 1){
    int t = (threadIdx.x >= off) ? sm[threadIdx.x - off] : 0;
    __syncthreads();
    sm[threadIdx.x] += t;
    __syncthreads();
  }
  if (threadIdx.x == 255) base = atomicAdd(ctr, sm[255]);
  __syncthreads();
  if (i < NN){
    int rs = base + sm[threadIdx.x] - v;
    rowstart[i] = rs; fill[i] = rs;
    dinv[i] = rsqrtf((float)v + 1.0f);   // +1 self loop
  }
}

__global__ void k_scatter(const int* __restrict__ ei, const int* __restrict__ ew,
                          int* __restrict__ fill, int* __restrict__ csr){
  int e = blockIdx.x*256 + threadIdx.x;
  if (e < EE && ew[e] == 1){
    int c = ei[EE + e];
    int pos = atomicAdd(&fill[c], 1);
    csr[pos] = ei[e];
  }
}

// ---------- GEMM1: Y1 = bf16(x@W1 + b1), stats accumulate.
//   128x32 tile, 256 thr, 4x4/thread, xt transposed bf16 k-major ----------
__global__ __launch_bounds__(256) void k_gemm1(const float* __restrict__ x,
    const float* __restrict__ W1, const float* __restrict__ b1,
    unsigned short* __restrict__ Y1b, float* __restrict__ stats){
  __shared__ unsigned short xt[128*128];  // [k][row] bf16, 32 KB
  __shared__ float Ws[128*32];            // [k][col] 16 KB
  __shared__ float red[64];
  const int tid = threadIdx.x;
  #pragma unroll
  for (int j = 0; j < 4; j++)
    ((float4*)Ws)[tid + j*256] = ((const float4*)W1)[tid + j*256];
  if (tid < 64) red[tid] = 0.f;
  const int row = tid >> 1;
  const int kh  = (tid & 1) * 64;
  const long grow = (long)blockIdx.x*128 + row;
  {
    const float4* xsrc = (const float4*)(x + grow*128LL + kh);
    const bool valid = grow < NN;
    #pragma unroll
    for (int i = 0; i < 16; i++){
      float4 v = valid ? xsrc[i] : float4{0.f,0.f,0.f,0.f};
      const int k = kh + i*4;
      xt[(k+0)*128 + row] = f2bf(v.x);
      xt[(k+1)*128 + row] = f2bf(v.y);
      xt[(k+2)*128 + row] = f2bf(v.z);
      xt[(k+3)*128 + row] = f2bf(v.w);
    }
  }
  __syncthreads();
  const int rg = tid >> 3, cg = tid & 7;   // 32 row-groups x 8 col-groups
  const float4 bv = ((const float4*)b1)[cg];
  float acc[4][4];
  #pragma unroll
  for (int i = 0; i < 4; i++){ acc[i][0]=bv.x; acc[i][1]=bv.y; acc[i][2]=bv.z; acc[i][3]=bv.w; }
  #pragma unroll 4
  for (int k = 0; k < 128; k++){
    const ushort4 ab = *(const ushort4*)&xt[k*128 + rg*4];
    const float4 w = *(const float4*)&Ws[k*32 + cg*4];
    const float a0 = bf2f(ab.x), a1 = bf2f(ab.y), a2 = bf2f(ab.z), a3 = bf2f(ab.w);
    acc[0][0]=fmaf(a0,w.x,acc[0][0]); acc[0][1]=fmaf(a0,w.y,acc[0][1]);
    acc[0][2]=fmaf(a0,w.z,acc[0][2]); acc[0][3]=fmaf(a0,w.w,acc[0][3]);
    acc[1][0]=fmaf(a1,w.x,acc[1][0]); acc[1][1]=fmaf(a1,w.y,acc[1][1]);
    acc[1][2]=fmaf(a1,w.z,acc[1][2]); acc[1][3]=fmaf(a1,w.w,acc[1][3]);
    acc[2][0]=fmaf(a2,w.x,acc[2][0]); acc[2][1]=fmaf(a2,w.y,acc[2][1]);
    acc[2][2]=fmaf(a2,w.z,acc[2][2]); acc[2][3]=fmaf(a2,w.w,acc[2][3]);
    acc[3][0]=fmaf(a3,w.x,acc[3][0]); acc[3][1]=fmaf(a3,w.y,acc[3][1]);
    acc[3][2]=fmaf(a3,w.z,acc[3][2]); acc[3][3]=fmaf(a3,w.w,acc[3][3]);
  }
  float s[4] = {0,0,0,0}, q[4] = {0,0,0,0};
  const long rbase = (long)blockIdx.x*128 + rg*4;
  #pragma unroll
  for (int i = 0; i < 4; i++){
    const long r = rbase + i;
    if (r < NN){
      ushort4 o; o.x=f2bf(acc[i][0]); o.y=f2bf(acc[i][1]); o.z=f2bf(acc[i][2]); o.w=f2bf(acc[i][3]);
      ((ushort4*)Y1b)[r*8 + cg] = o;
      #pragma unroll
      for (int j = 0; j < 4; j++){ s[j] += acc[i][j]; q[j] += acc[i][j]*acc[i][j]; }
    }
  }
  __syncthreads();
  #pragma unroll
  for (int j = 0; j < 4; j++){
    atomicAdd(&red[cg*4+j], s[j]);
    atomicAdd(&red[32+cg*4+j], q[j]);
  }
  __syncthreads();
  if (tid < 64) atomicAdd(&stats[tid], red[tid]);
}

// ---------- MLP2: Y2 = bf16(relu(bn1(Y1))@W2 + b2), stats2 accumulate.
//   128x32 tile, 4x4/thread, BN+ReLU fused into transposed fill ----------
__global__ __launch_bounds__(256) void k_mlp2(const unsigned short* __restrict__ Y1b,
    const float* __restrict__ W2, const float* __restrict__ b2,
    const float* __restrict__ g1, const float* __restrict__ bt1,
    float* __restrict__ stats, unsigned short* __restrict__ Y2b){
  __shared__ float ht[32*128];   // [k][row] f32 16 KB (post BN+ReLU)
  __shared__ float Ws[32*32];    // [k][col] 4 KB
  __shared__ float red[64];
  __shared__ float scs[32], shs[32];
  const int tid = threadIdx.x;
  ((float4*)Ws)[tid] = ((const float4*)W2)[tid];
  if (tid < 64) red[tid] = 0.f;
  if (tid < 32){
    float mean = stats[tid] * (1.0f/NN);
    float var  = stats[32 + tid] * (1.0f/NN) - mean*mean;
    float sH = g1[tid] * rsqrtf(fmaxf(var, 0.0f) + BN_EPS);
    scs[tid] = sH; shs[tid] = bt1[tid] - mean*sH;
  }
  __syncthreads();   // scs/shs ready
  const int row = tid >> 1;
  const int kh  = (tid & 1) * 16;
  const long grow = (long)blockIdx.x*128 + row;
  {
    const uint4* src = (const uint4*)(Y1b + grow*32LL + kh);
    const bool valid = grow < NN;
    #pragma unroll
    for (int i = 0; i < 2; i++){
      uint4 u = valid ? src[i] : uint4{0,0,0,0};
      const unsigned short* us = (const unsigned short*)&u;
      #pragma unroll
      for (int j = 0; j < 8; j++){
        const int k = kh + i*8 + j;
        ht[k*128 + row] = fmaxf(fmaf(bf2f(us[j]), scs[k], shs[k]), 0.f);
      }
    }
  }
  __syncthreads();
  const int rg = tid >> 3, cg = tid & 7;
  const float4 bv = ((const float4*)b2)[cg];
  float acc[4][4];
  #pragma unroll
  for (int i = 0; i < 4; i++){ acc[i][0]=bv.x; acc[i][1]=bv.y; acc[i][2]=bv.z; acc[i][3]=bv.w; }
  #pragma unroll 8
  for (int k = 0; k < 32; k++){
    const float4 a = *(const float4*)&ht[k*128 + rg*4];
    const float4 w = *(const float4*)&Ws[k*32 + cg*4];
    acc[0][0]=fmaf(a.x,w.x,acc[0][0]); acc[0][1]=fmaf(a.x,w.y,acc[0][1]);
    acc[0][2]=fmaf(a.x,w.z,acc[0][2]); acc[0][3]=fmaf(a.x,w.w,acc[0][3]);
    acc[1][0]=fmaf(a.y,w.x,acc[1][0]); acc[1][1]=fmaf(a.y,w.y,acc[1][1]);
    acc[1][2]=fmaf(a.y,w.z,acc[1][2]); acc[1][3]=fmaf(a.y,w.w,acc[1][3]);
    acc[2][0]=fmaf(a.z,w.x,acc[2][0]); acc[2][1]=fmaf(a.z,w.y,acc[2][1]);
    acc[2][2]=fmaf(a.z,w.z,acc[2][2]); acc[2][3]=fmaf(a.z,w.w,acc[2][3]);
    acc[3][0]=fmaf(a.w,w.x,acc[3][0]); acc[3][1]=fmaf(a.w,w.y,acc[3][1]);
    acc[3][2]=fmaf(a.w,w.z,acc[3][2]); acc[3][3]=fmaf(a.w,w.w,acc[3][3]);
  }
  float s[4] = {0,0,0,0}, q[4] = {0,0,0,0};
  const long rbase = (long)blockIdx.x*128 + rg*4;
  #pragma unroll
  for (int i = 0; i < 4; i++){
    const long r = rbase + i;
    if (r < NN){
      ushort4 o; o.x=f2bf(acc[i][0]); o.y=f2bf(acc[i][1]); o.z=f2bf(acc[i][2]); o.w=f2bf(acc[i][3]);
      ((ushort4*)Y2b)[r*8 + cg] = o;
      #pragma unroll
      for (int j = 0; j < 4; j++){ s[j] += acc[i][j]; q[j] += acc[i][j]*acc[i][j]; }
    }
  }
  __syncthreads();
  #pragma unroll
  for (int j = 0; j < 4; j++){
    atomicAdd(&red[cg*4+j], s[j]);
    atomicAdd(&red[32+cg*4+j], q[j]);
  }
  __syncthreads();
  if (tid < 64) atomicAdd(&stats[128 + tid], red[tid]);
}

// ---------- layer0: h1 = relu(bn2(Y2)) (BN inlined); Pool0 <- max(h1@Wl0+bl0);
//            Hs1 = bf16((h1@Wg1)*dinv) ----------
__global__ __launch_bounds__(256) void k_layer0(const unsigned short* __restrict__ Y2b,
    const float* __restrict__ stats, const float* __restrict__ g2,
    const float* __restrict__ bt2, const float* __restrict__ Wg1,
    const float* __restrict__ Wl0, const float* __restrict__ bl0,
    const float* __restrict__ dinv, const int* __restrict__ batch,
    unsigned short* __restrict__ Hs1, unsigned* __restrict__ Pool0){
  __shared__ float hs[32*36];
  __shared__ float Wg[32*64];
  __shared__ float Wl[320];
  __shared__ float bl[10];
  __shared__ float scs[32], shs[32];
  const int tid = threadIdx.x;
  ((float4*)Wg)[tid]       = ((const float4*)Wg1)[tid];
  ((float4*)Wg)[tid + 256] = ((const float4*)Wg1)[tid + 256];
  for (int j = tid; j < 320; j += 256) Wl[j] = Wl0[j];
  if (tid < 10)  bl[tid] = bl0[tid];
  if (tid < 32){
    float mean = stats[128 + tid] * (1.0f/NN);
    float var  = stats[160 + tid] * (1.0f/NN) - mean*mean;
    float s = g2[tid] * rsqrtf(fmaxf(var, 0.0f) + BN_EPS);
    scs[tid] = s; shs[tid] = bt2[tid] - mean*s;
  }
  __syncthreads();
  {
    const int rr = tid >> 3, kk = tid & 7;
    const float4 sc = *(const float4*)&scs[kk*4];
    const float4 sh = *(const float4*)&shs[kk*4];
    ushort4 u = ((const ushort4*)Y2b)[(size_t)blockIdx.x*256 + tid];
    float4 v;
    v.x = fmaxf(fmaf(bf2f(u.x), sc.x, sh.x), 0.f);
    v.y = fmaxf(fmaf(bf2f(u.y), sc.y, sh.y), 0.f);
    v.z = fmaxf(fmaf(bf2f(u.z), sc.z, sh.z), 0.f);
    v.w = fmaxf(fmaf(bf2f(u.w), sc.w, sh.w), 0.f);
    *(float4*)&hs[rr*36 + kk*4] = v;
  }
  __syncthreads();
  const int w = tid >> 6, f = tid & 63;
  for (int i = 0; i < 8; i++){
    const int r = w*8 + i;
    const int row = blockIdx.x*32 + r;
    const float* hr = &hs[r*36];
    float acc = 0.f;
    #pragma unroll
    for (int k = 0; k < 32; k++) acc += hr[k]*Wg[k*64 + f];
    Hs1[(size_t)row*64 + f] = f2bf(acc * dinv[row]);
    if (f < 10){
      float p = bl[f];
      #pragma unroll
      for (int k = 0; k < 32; k++) p += hr[k]*Wl[k*10 + f];
      atomicMax(&Pool0[batch[row]*10 + f], encf(p));
    }
  }
}

// ---------- shared gather body: acc = sum of Hs rows (8-way unrolled) ----------
__device__ __forceinline__ float gather_sum(const unsigned short* __restrict__ Hs,
    const int* __restrict__ csr, int s, int e, int f){
  float acc = 0.f;
  int j = s;
  for (; j + 7 < e; j += 8){
    const int r0 = csr[j],   r1 = csr[j+1], r2 = csr[j+2], r3 = csr[j+3];
    const int r4 = csr[j+4], r5 = csr[j+5], r6 = csr[j+6], r7 = csr[j+7];
    float t0 = bf2f(Hs[(size_t)r0*64 + f]);
    float t1 = bf2f(Hs[(size_t)r1*64 + f]);
    float t2 = bf2f(Hs[(size_t)r2*64 + f]);
    float t3 = bf2f(Hs[(size_t)r3*64 + f]);
    float t4 = bf2f(Hs[(size_t)r4*64 + f]);
    float t5 = bf2f(Hs[(size_t)r5*64 + f]);
    float t6 = bf2f(Hs[(size_t)r6*64 + f]);
    float t7 = bf2f(Hs[(size_t)r7*64 + f]);
    acc += ((t0 + t1) + (t2 + t3)) + ((t4 + t5) + (t6 + t7));
  }
  for (; j + 3 < e; j += 4){
    const int r0 = csr[j], r1 = csr[j+1], r2 = csr[j+2], r3 = csr[j+3];
    float t0 = bf2f(Hs[(size_t)r0*64 + f]);
    float t1 = bf2f(Hs[(size_t)r1*64 + f]);
    float t2 = bf2f(Hs[(size_t)r2*64 + f]);
    float t3 = bf2f(Hs[(size_t)r3*64 + f]);
    acc += (t0 + t1) + (t2 + t3);
  }
  for (; j < e; j++) acc += bf2f(Hs[(size_t)csr[j]*64 + f]);
  return acc;
}

// ---------- pool epilogue: LDS-combine 4 nodes/block (batch sorted) ----------
__device__ __forceinline__ void pool_epilogue(float h, int w, int f, int c,
    const int* __restrict__ batch, unsigned* __restrict__ Pool,
    float (*sm)[64], int* sb){
  sm[w][f] = h;
  if (f == 0) sb[w] = batch[c];
  __syncthreads();
  if (w == 0){
    const int b0 = sb[0], b1 = sb[1], b2 = sb[2], b3 = sb[3];
    if (b0 == b3){
      float m = fmaxf(fmaxf(sm[0][f], sm[1][f]), fmaxf(sm[2][f], sm[3][f]));
      atomicMax(&Pool[b0*64 + f], encf(m));
    } else {
      atomicMax(&Pool[b0*64 + f], encf(sm[0][f]));
      atomicMax(&Pool[b1*64 + f], encf(sm[1][f]));
      atomicMax(&Pool[b2*64 + f], encf(sm[2][f]));
      atomicMax(&Pool[b3*64 + f], encf(sm[3][f]));
    }
  }
}

// ---------- agg1: h2 = dc*(sum Hs1[r] + Hs1[c]) + bg1; pool; store bf16 h2 ----------
__global__ __launch_bounds__(256) void k_agg1(const unsigned short* __restrict__ Hs,
    const float* __restrict__ dinv, const int* __restrict__ rowstart,
    const int* __restrict__ cnt, const int* __restrict__ csr,
    const float* __restrict__ bias, const int* __restrict__ batch,
    unsigned short* __restrict__ H2b, unsigned* __restrict__ Pool){
  __shared__ float sm[4][64];
  __shared__ int sb[4];
  const int w = threadIdx.x >> 6, f = threadIdx.x & 63;
  const int c = blockIdx.x*4 + w;
  const int s = rowstart[c], e = s + cnt[c];
  float acc = gather_sum(Hs, csr, s, e, f);
  const float dc = dinv[c];
  const float h = fmaf(acc + bf2f(Hs[(size_t)c*64 + f]), dc, bias[f]);
  H2b[(size_t)c*64 + f] = f2bf(h);
  pool_epilogue(h, w, f, c, batch, Pool, sm, sb);
}

// ---------- agg2: h3 = dc*(sum Hs2[r] + Hs2[c]) + bg2; pool only ----------
__global__ __launch_bounds__(256) void k_agg2(const unsigned short* __restrict__ Hs,
    const float* __restrict__ dinv, const int* __restrict__ rowstart,
    const int* __restrict__ cnt, const int* __restrict__ csr,
    const float* __restrict__ bias, const int* __restrict__ batch,
    unsigned* __restrict__ Pool){
  __shared__ float sm[4][64];
  __shared__ int sb[4];
  const int w = threadIdx.x >> 6, f = threadIdx.x & 63;
  const int c = blockIdx.x*4 + w;
  const int s = rowstart[c], e = s + cnt[c];
  float acc = gather_sum(Hs, csr, s, e, f);
  const float dc = dinv[c];
  const float h = fmaf(acc + bf2f(Hs[(size_t)c*64 + f]), dc, bias[f]);
  pool_epilogue(h, w, f, c, batch, Pool, sm, sb);
}

// ---------- layer1 GEMM: Hs2 = bf16((h2 @ Wg2) * dinv) ----------
__global__ __launch_bounds__(256) void k_layer1(const unsigned short* __restrict__ H2b,
    const float* __restrict__ Wg2, const float* __restrict__ dinv,
    unsigned short* __restrict__ Hs2){
  __shared__ float as[32*68];
  __shared__ float Wg[64*64];
  const int tid = threadIdx.x;
  #pragma unroll
  for (int j = 0; j < 4; j++) ((float4*)Wg)[tid + j*256] = ((const float4*)Wg2)[tid + j*256];
  {
    // 32 rows x 64 bf16 = 2048 ushorts; 8 per thread
    const int rr = tid >> 3, kk = tid & 7;
    ushort4 v0 = ((const ushort4*)H2b)[(size_t)blockIdx.x*512 + tid*2];
    ushort4 v1 = ((const ushort4*)H2b)[(size_t)blockIdx.x*512 + tid*2 + 1];
    float* dst = &as[rr*68 + kk*8];
    dst[0]=bf2f(v0.x); dst[1]=bf2f(v0.y); dst[2]=bf2f(v0.z); dst[3]=bf2f(v0.w);
    dst[4]=bf2f(v1.x); dst[5]=bf2f(v1.y); dst[6]=bf2f(v1.z); dst[7]=bf2f(v1.w);
  }
  __syncthreads();
  const int w = tid >> 6, f = tid & 63;
  for (int i = 0; i < 8; i++){
    const int r = w*8 + i;
    const int row = blockIdx.x*32 + r;
    const float* ar = &as[r*68];
    float acc = 0.f;
    #pragma unroll
    for (int k = 0; k < 64; k++) acc += ar[k]*Wg[k*64 + f];
    Hs2[(size_t)row*64 + f] = f2bf(acc * dinv[row]);
  }
}

// ---------- final: out = P0 + P1@Wl1+bl1 + P2@Wl2+bl2 ----------
__global__ __launch_bounds__(256) void k_final(const unsigned* __restrict__ P0,
    const unsigned* __restrict__ P1, const unsigned* __restrict__ P2,
    const float* __restrict__ Wl1, const float* __restrict__ bl1,
    const float* __restrict__ Wl2, const float* __restrict__ bl2,
    float* __restrict__ out){
  const int t = blockIdx.x*256 + threadIdx.x;
  const int g = t >> 4, c = t & 15;
  if (g >= GG || c >= 10) return;
  float acc = dec0(P0[g*10 + c]) + bl1[c] + bl2[c];
  for (int f = 0; f < 64; f++){
    acc += dec0(P1[g*64 + f]) * Wl1[f*10 + c];
    acc += dec0(P2[g*64 + f]) * Wl2[f*10 + c];
  }
  out[g*10 + c] = acc;
}

extern "C" void kernel_launch(void* const* d_in, const int* in_sizes, int n_in,
                              void* d_out, int out_size, void* d_ws, size_t ws_size,
                              hipStream_t stream){
  const float* x   = (const float*)d_in[0];
  const int*   ei  = (const int*)d_in[1];
  const int*   ew  = (const int*)d_in[2];
  const int*   bat = (const int*)d_in[3];
  const float* W1  = (const float*)d_in[5],  *b1  = (const float*)d_in[6];
  const float* g1  = (const float*)d_in[7],  *bt1 = (const float*)d_in[8];
  const float* W2  = (const float*)d_in[9],  *b2  = (const float*)d_in[10];
  const float* g2  = (const float*)d_in[11], *bt2 = (const float*)d_in[12];
  const float* Wl0 = (const float*)d_in[13], *bl0 = (const float*)d_in[14];
  const float* Wg1 = (const float*)d_in[15], *bg1 = (const float*)d_in[16];
  const float* Wl1 = (const float*)d_in[17], *bl1 = (const float*)d_in[18];
  const float* Wg2 = (const float*)d_in[19], *bg2 = (const float*)d_in[20];
  const float* Wl2 = (const float*)d_in[21], *bl2 = (const float*)d_in[22];

  float* ws = (float*)d_ws;
  // workspace layout (4B elems). Zeroed prefix: cnt | ctr | stats | P0 | P1 | P2
  const size_t oCnt   = 0;                         // NN ints
  const size_t oCtr   = NN;                        // 8 (cursor + pad)
  const size_t oStats = NN + 8;                    // 256
  const size_t oP0    = oStats + 256;              // G*10
  const size_t oP1    = oP0 + (size_t)GG*10;       // G*64
  const size_t oP2    = oP1 + (size_t)GG*64;       // G*64
  const size_t oZEnd  = oP2 + (size_t)GG*64;       // zero prefix end
  const size_t oDinv  = oZEnd;                     // NN
  const size_t oRS    = oDinv + NN;                // NN
  const size_t oFill  = oRS + NN;                  // NN
  const size_t oCsr   = oFill + NN;                // EE
  const size_t oR1    = oCsr + EE;                 // NN*16 (Y1b bf16: NN*32)
  const size_t oR2    = oR1 + (size_t)NN*16;       // NN*16 (Y2b bf16: NN*32)
  const size_t oR3    = oR2 + (size_t)NN*16;       // NN*32 (Hs1 bf16: NN*64; later Hs2)
  const size_t oR4    = oR3 + (size_t)NN*32;       // NN*32 (H2b bf16: NN*64)

  int*   cnt   = (int*)(ws + oCnt);
  int*   ctr   = (int*)(ws + oCtr);
  float* stats = ws + oStats;
  unsigned* P0 = (unsigned*)(ws + oP0);
  unsigned* P1 = (unsigned*)(ws + oP1);
  unsigned* P2 = (unsigned*)(ws + oP2);
  float* dinv  = ws + oDinv;
  int*   rs    = (int*)(ws + oRS);
  int*   fill  = (int*)(ws + oFill);
  int*   csr   = (int*)(ws + oCsr);
  unsigned short* Y1b = (unsigned short*)(ws + oR1);
  unsigned short* Y2b = (unsigned short*)(ws + oR2);
  unsigned short* Hs1 = (unsigned short*)(ws + oR3);
  unsigned short* Hs2 = (unsigned short*)(ws + oR3);   // reuse after Hs1 consumed
  unsigned short* H2b = (unsigned short*)(ws + oR4);

  (void)hipMemsetAsync(d_ws, 0, oZEnd*sizeof(float), stream);

  // CSR build (arbitrary range packing — gather only sums)
  k_count  <<<EE/256, 256, 0, stream>>>(ei, ew, cnt);
  k_alloc  <<<NB1, 256, 0, stream>>>(cnt, ctr, dinv, rs, fill);
  k_scatter<<<EE/256, 256, 0, stream>>>(ei, ew, fill, csr);

  // MLP + heads
  k_gemm1<<<NTB, 256, 0, stream>>>(x, W1, b1, Y1b, stats);
  k_mlp2 <<<NTB, 256, 0, stream>>>(Y1b, W2, b2, g1, bt1, stats, Y2b);
  k_layer0<<<3125, 256, 0, stream>>>(Y2b, stats, g2, bt2, Wg1, Wl0, bl0, dinv, bat, Hs1, P0);
  k_agg1 <<<NN/4, 256, 0, stream>>>(Hs1, dinv, rs, cnt, csr, bg1, bat, H2b, P1);
  k_layer1<<<3125, 256, 0, stream>>>(H2b, Wg2, dinv, Hs2);
  k_agg2 <<<NN/4, 256, 0, stream>>>(Hs2, dinv, rs, cnt, csr, bg2, bat, P2);
  k_final<<<(GG*16 + 255)/256, 256, 0, stream>>>(P0, P1, P2, Wl1, bl1, Wl2, bl2, (float*)d_out);
}